// Round 1
// baseline (62299.170 us; speedup 1.0000x reference)
//
#include <hip/hip_runtime.h>
#include <hip/hip_bf16.h>

// ESN recurrence on MI355X.
// T=4096 steps, B=64 batch, I=128, H=1024. out = h_T [64,1024] fp32.
//
// Structure: 64 blocks x 256 threads (4 waves). Wave (m, n_idx) owns the
// 16x16 output tile rows m*16..+15 (batch), cols n_idx*16..+15 (hidden).
// Whh/Wih N-slices live in registers as hi/lo split bf16 (exact to ~2^-17).
// h is double-buffered bf16 in d_ws; per-step sync is a per-m-group
// (16 block) device-scope atomic barrier.

#define TT 4096
#define BB 64
#define II 128
#define HH 1024

typedef short bf16x8 __attribute__((ext_vector_type(8)));
typedef float f32x4 __attribute__((ext_vector_type(4)));

__device__ __forceinline__ unsigned short f2bf(float f) {
    unsigned int u = __float_as_uint(f);
    u += 0x7FFFu + ((u >> 16) & 1u);   // RNE
    return (unsigned short)(u >> 16);
}
__device__ __forceinline__ float bf2f(unsigned short s) {
    return __uint_as_float(((unsigned int)s) << 16);
}

__global__ __launch_bounds__(256, 1) void esn_kernel(
    const float* __restrict__ x, const float* __restrict__ wih,
    const float* __restrict__ whh, const float* __restrict__ bih,
    const float* __restrict__ bhh, float* __restrict__ out,
    unsigned short* __restrict__ hb0, unsigned short* __restrict__ hb1,
    unsigned int* __restrict__ cnt)
{
    // padded LDS: row pitch 1032 shorts (2064 B) -> bank offset 4/row, no
    // 16-way conflicts on ds_read_b128 fragment reads.
    __shared__ __align__(16) unsigned short h_lds[16 * 1032];
    __shared__ __align__(16) unsigned short x_lds[16 * 136];

    const int tid  = threadIdx.x;
    const int lane = tid & 63;
    const int wv   = tid >> 6;      // wave 0..3
    const int col  = lane & 15;     // MFMA col index (n within tile / A row m)
    const int quad = lane >> 4;     // 0..3

    const int blk    = blockIdx.x;
    const int m      = blk >> 4;            // batch group 0..3
    const int m_base = m * 16;
    const int n_idx  = (blk & 15) * 4 + wv; // 0..63
    const int n_base = n_idx * 16;

    // ---- one-time: weights into registers, hi/lo bf16 split ----
    bf16x8 bh[32], bl[32], ih_h[4], ih_l[4];
#pragma unroll
    for (int kt = 0; kt < 32; ++kt) {
        const float* p = whh + (size_t)(n_base + col) * HH + kt * 32 + quad * 8;
        bf16x8 hi, lo;
#pragma unroll
        for (int j = 0; j < 8; ++j) {
            float v = p[j];
            unsigned short h16 = f2bf(v);
            hi[j] = (short)h16;
            lo[j] = (short)f2bf(v - bf2f(h16));
        }
        bh[kt] = hi; bl[kt] = lo;
    }
#pragma unroll
    for (int kt = 0; kt < 4; ++kt) {
        const float* p = wih + (size_t)(n_base + col) * II + kt * 32 + quad * 8;
        bf16x8 hi, lo;
#pragma unroll
        for (int j = 0; j < 8; ++j) {
            float v = p[j];
            unsigned short h16 = f2bf(v);
            hi[j] = (short)h16;
            lo[j] = (short)f2bf(v - bf2f(h16));
        }
        ih_h[kt] = hi; ih_l[kt] = lo;
    }
    const float bias_sum = bih[n_base + col] + bhh[n_base + col];

    // staging indices (256 threads cover the 16x1024 h tile / 16x128 x tile)
    const int sr = tid >> 4;           // row 0..15
    const int sc = (tid & 15) * 64;    // 64 shorts per thread
    const int xc = (tid & 15) * 8;     // 8 floats per thread

    for (int t = 0; t < TT; ++t) {
        const unsigned short* rb = (t & 1) ? hb1 : hb0;
        unsigned short*       wb = (t & 1) ? hb0 : hb1;

        // stage h m-tile (16x1024 bf16) global -> LDS (padded)
        {
            const unsigned short* gp = rb + (size_t)(m_base + sr) * HH + sc;
            unsigned short*       lp = h_lds + sr * 1032 + sc;
#pragma unroll
            for (int j = 0; j < 8; ++j)
                *(bf16x8*)(lp + 8 * j) = *(const bf16x8*)(gp + 8 * j);
        }
        // stage x_t m-tile (16x128 fp32 -> bf16) -> LDS
        {
            const float* gp = x + (size_t)t * (BB * II) + (size_t)(m_base + sr) * II + xc;
            bf16x8 v;
#pragma unroll
            for (int j = 0; j < 8; ++j) v[j] = (short)f2bf(gp[j]);
            *(bf16x8*)(x_lds + sr * 136 + xc) = v;
        }
        __syncthreads();

        f32x4 acc = {0.f, 0.f, 0.f, 0.f};
        const unsigned short* arow = h_lds + col * 1032;
#pragma unroll
        for (int kt = 0; kt < 32; ++kt) {
            bf16x8 a = *(const bf16x8*)(arow + kt * 32 + quad * 8);
            acc = __builtin_amdgcn_mfma_f32_16x16x32_bf16(a, bh[kt], acc, 0, 0, 0);
            acc = __builtin_amdgcn_mfma_f32_16x16x32_bf16(a, bl[kt], acc, 0, 0, 0);
        }
        const unsigned short* xrow = x_lds + col * 136;
#pragma unroll
        for (int kt = 0; kt < 4; ++kt) {
            bf16x8 a = *(const bf16x8*)(xrow + kt * 32 + quad * 8);
            acc = __builtin_amdgcn_mfma_f32_16x16x32_bf16(a, ih_h[kt], acc, 0, 0, 0);
            acc = __builtin_amdgcn_mfma_f32_16x16x32_bf16(a, ih_l[kt], acc, 0, 0, 0);
        }

        // epilogue: bias + tanh, write bf16 h (and fp32 out on last step)
        // C/D layout: col = lane&15, row = quad*4 + i
#pragma unroll
        for (int i = 0; i < 4; ++i) {
            float pre = acc[i] + bias_sum;
            float pc  = fminf(fmaxf(pre, -9.f), 9.f);
            float e   = __expf(2.f * pc);
            float th  = (e - 1.f) / (e + 1.f);
            int row   = m_base + quad * 4 + i;
            wb[(size_t)row * HH + n_base + col] = f2bf(th);
            if (t == TT - 1) out[(size_t)row * HH + n_base + col] = th;
        }

        if (t < TT - 1) {
            __threadfence();               // flush h stores to coherent point
            __syncthreads();               // all waves' fences done
            if (tid == 0) {
                __hip_atomic_fetch_add(&cnt[m], 1u, __ATOMIC_ACQ_REL,
                                       __HIP_MEMORY_SCOPE_AGENT);
                const unsigned int target = 16u * (unsigned int)(t + 1);
                while (__hip_atomic_load(&cnt[m], __ATOMIC_ACQUIRE,
                                         __HIP_MEMORY_SCOPE_AGENT) < target) {}
            }
            __syncthreads();
            __threadfence();               // invalidate L1/L2 before next stage
        }
    }
}

extern "C" void kernel_launch(void* const* d_in, const int* in_sizes, int n_in,
                              void* d_out, int out_size, void* d_ws, size_t ws_size,
                              hipStream_t stream) {
    const float* x   = (const float*)d_in[0];
    const float* wih = (const float*)d_in[1];
    const float* whh = (const float*)d_in[2];
    const float* bih = (const float*)d_in[3];
    const float* bhh = (const float*)d_in[4];
    float* out = (float*)d_out;

    unsigned short* hb0 = (unsigned short*)d_ws;                    // 128 KB
    unsigned short* hb1 = hb0 + (size_t)BB * HH;                    // 128 KB
    unsigned int*   cnt = (unsigned int*)((char*)d_ws + 262144);    // 4 u32

    // zero h_buf0 (h0 = 0) and the barrier counters (ws is poisoned 0xAA)
    hipMemsetAsync(d_ws, 0, 262144 + 64, stream);

    esn_kernel<<<dim3(64), dim3(256), 0, stream>>>(x, wih, whh, bih, bhh,
                                                   out, hb0, hb1, cnt);
}

// Round 2
// 33923.917 us; speedup vs baseline: 1.8364x; 1.8364x over previous
//
#include <hip/hip_runtime.h>
#include <hip/hip_bf16.h>

// ESN recurrence on MI355X — R2: fence-free LLC-coherent h exchange.
// T=4096 steps, B=64, I=128, H=1024. out = h_T [64,1024] fp32.
//
// 64 blocks x 256 threads (4 waves). Wave (m, n_idx) owns output tile
// rows m*16..+15 (batch), cols n_idx*16..+15 (hidden). Whh/Wih N-slices
// in registers as hi/lo split bf16. h double-buffered as packed-u32 bf16
// pairs in d_ws, moved with RELAXED agent-scope atomics (coherent at LLC,
// no wbl2/inv fences). Per-step sync: per-block epoch flags, relaxed polls.

#define TT 4096
#define BB 64
#define II 128
#define HH 1024

typedef short bf16x8 __attribute__((ext_vector_type(8)));
typedef float f32x4 __attribute__((ext_vector_type(4)));

__device__ __forceinline__ unsigned short f2bf(float f) {
    unsigned int u = __float_as_uint(f);
    u += 0x7FFFu + ((u >> 16) & 1u);   // RNE
    return (unsigned short)(u >> 16);
}
__device__ __forceinline__ float bf2f(unsigned short s) {
    return __uint_as_float(((unsigned int)s) << 16);
}

__global__ __launch_bounds__(256, 1) void esn_kernel(
    const float* __restrict__ x, const float* __restrict__ wih,
    const float* __restrict__ whh, const float* __restrict__ bih,
    const float* __restrict__ bhh, float* __restrict__ out,
    unsigned int* __restrict__ hbu0, unsigned int* __restrict__ hbu1,
    unsigned int* __restrict__ flags)
{
    // pitch 1032 shorts/row; 16B chunks swizzled: phys=(L&~7)|((L&7 + L>>3)&7)
    __shared__ __align__(16) unsigned short h_lds[16 * 1032];
    __shared__ __align__(16) unsigned short x_lds[16 * 136];

    const int tid  = threadIdx.x;
    const int lane = tid & 63;
    const int wv   = tid >> 6;
    const int col  = lane & 15;     // MFMA col (n) / A row (m)
    const int quad = lane >> 4;

    const int blk    = blockIdx.x;
    const int m      = blk >> 4;            // batch group 0..3
    const int m_base = m * 16;
    const int jj     = blk & 15;            // index within group
    const int n_idx  = jj * 4 + wv;
    const int n_base = n_idx * 16;

    // ---- one-time: weights into registers, hi/lo bf16 split ----
    bf16x8 bh[32], bl[32], ih_h[4], ih_l[4];
#pragma unroll
    for (int kt = 0; kt < 32; ++kt) {
        const float* p = whh + (size_t)(n_base + col) * HH + kt * 32 + quad * 8;
        bf16x8 hi, lo;
#pragma unroll
        for (int j = 0; j < 8; ++j) {
            float v = p[j];
            unsigned short h16 = f2bf(v);
            hi[j] = (short)h16;
            lo[j] = (short)f2bf(v - bf2f(h16));
        }
        bh[kt] = hi; bl[kt] = lo;
    }
#pragma unroll
    for (int kt = 0; kt < 4; ++kt) {
        const float* p = wih + (size_t)(n_base + col) * II + kt * 32 + quad * 8;
        bf16x8 hi, lo;
#pragma unroll
        for (int j = 0; j < 8; ++j) {
            float v = p[j];
            unsigned short h16 = f2bf(v);
            hi[j] = (short)h16;
            lo[j] = (short)f2bf(v - bf2f(h16));
        }
        ih_h[kt] = hi; ih_l[kt] = lo;
    }
    const float bias_sum = bih[n_base + col] + bhh[n_base + col];

    const int sr = tid >> 4;         // staging row 0..15
    const int sc = tid & 15;         // staging col group 0..15
    const unsigned int* fl = flags + m * 16;

    for (int t = 0; t < TT; ++t) {
        const unsigned int* rbu = (t & 1) ? hbu1 : hbu0;
        unsigned int*       wbu = (t & 1) ? hbu0 : hbu1;

        // stage x_t (16x128 fp32 -> bf16) -> LDS (overlaps flag latency)
        {
            const float* gp = x + (size_t)t * (BB * II) + (size_t)(m_base + sr) * II + sc * 8;
            bf16x8 v;
#pragma unroll
            for (int j = 0; j < 8; ++j) v[j] = (short)f2bf(gp[j]);
            *(bf16x8*)(x_lds + sr * 136 + sc * 8) = v;
        }

        // wait for h^t from the other 15 blocks of this group (wave 0 polls)
        if (t > 0 && wv == 0) {
            const bool skip = (lane >= 16) || (lane == jj);
            for (;;) {
                unsigned int v = 0xFFFFFFFFu;
                if (!skip)
                    v = __hip_atomic_load(fl + lane, __ATOMIC_RELAXED,
                                          __HIP_MEMORY_SCOPE_AGENT);
                if (__ballot(skip || v >= (unsigned int)t) == ~0ull) break;
            }
        }
        __syncthreads();

        // stage h^t m-tile (16 rows x 512 u32) -> LDS, swizzled chunks
        {
            const unsigned int* gp = rbu + (size_t)(m_base + sr) * (HH / 2) + sc * 32;
            unsigned int tmp[32];
#pragma unroll
            for (int k = 0; k < 32; ++k)
                tmp[k] = __hip_atomic_load(gp + k, __ATOMIC_RELAXED,
                                           __HIP_MEMORY_SCOPE_AGENT);
            unsigned short* lrow = h_lds + sr * 1032;
#pragma unroll
            for (int j = 0; j < 8; ++j)
                *(bf16x8*)(lrow + (sc * 8 + ((j + sc) & 7)) * 8) =
                    ((const bf16x8*)tmp)[j];
        }
        __syncthreads();

        f32x4 acc = {0.f, 0.f, 0.f, 0.f};
        const unsigned short* arow = h_lds + col * 1032;
#pragma unroll
        for (int kt = 0; kt < 32; ++kt) {
            // logical chunk L = kt*4+quad; phys = 8*(kt>>1) + ((4*(kt&1)+(kt>>1)+quad)&7)
            const int C = 4 * (kt & 1) + (kt >> 1);
            bf16x8 a = *(const bf16x8*)(arow + (kt >> 1) * 64 + ((C + quad) & 7) * 8);
            acc = __builtin_amdgcn_mfma_f32_16x16x32_bf16(a, bh[kt], acc, 0, 0, 0);
            acc = __builtin_amdgcn_mfma_f32_16x16x32_bf16(a, bl[kt], acc, 0, 0, 0);
        }
        const unsigned short* xrow = x_lds + col * 136;
#pragma unroll
        for (int kt = 0; kt < 4; ++kt) {
            bf16x8 a = *(const bf16x8*)(xrow + kt * 32 + quad * 8);
            acc = __builtin_amdgcn_mfma_f32_16x16x32_bf16(a, ih_h[kt], acc, 0, 0, 0);
            acc = __builtin_amdgcn_mfma_f32_16x16x32_bf16(a, ih_l[kt], acc, 0, 0, 0);
        }

        // epilogue: bias + tanh; pack bf16 pairs; even lanes store 4 u32
        float th[4];
#pragma unroll
        for (int i = 0; i < 4; ++i) {
            float pre = acc[i] + bias_sum;
            float pc  = fminf(fmaxf(pre, -9.f), 9.f);
            float e   = __expf(2.f * pc);
            th[i] = (e - 1.f) / (e + 1.f);
        }
        {
            unsigned int p01 = (unsigned int)f2bf(th[0]) |
                               ((unsigned int)f2bf(th[1]) << 16);
            unsigned int p23 = (unsigned int)f2bf(th[2]) |
                               ((unsigned int)f2bf(th[3]) << 16);
            unsigned int q01 = (unsigned int)__shfl_xor((int)p01, 1, 64);
            unsigned int q23 = (unsigned int)__shfl_xor((int)p23, 1, 64);
            if (!(lane & 1)) {
                unsigned int w0 = (p01 & 0xFFFFu) | (q01 << 16);
                unsigned int w1 = (p01 >> 16) | (q01 & 0xFFFF0000u);
                unsigned int w2 = (p23 & 0xFFFFu) | (q23 << 16);
                unsigned int w3 = (p23 >> 16) | (q23 & 0xFFFF0000u);
                const int ucol = (n_base + col) >> 1;
                unsigned int* wp = wbu + (size_t)(m_base + quad * 4) * (HH / 2) + ucol;
                __hip_atomic_store(wp,                w0, __ATOMIC_RELAXED, __HIP_MEMORY_SCOPE_AGENT);
                __hip_atomic_store(wp + (HH / 2),     w1, __ATOMIC_RELAXED, __HIP_MEMORY_SCOPE_AGENT);
                __hip_atomic_store(wp + 2 * (HH / 2), w2, __ATOMIC_RELAXED, __HIP_MEMORY_SCOPE_AGENT);
                __hip_atomic_store(wp + 3 * (HH / 2), w3, __ATOMIC_RELAXED, __HIP_MEMORY_SCOPE_AGENT);
            }
        }
        if (t == TT - 1) {
#pragma unroll
            for (int i = 0; i < 4; ++i)
                out[(size_t)(m_base + quad * 4 + i) * HH + n_base + col] = th[i];
        }

        // all waves' stores drained (syncthreads emits vmcnt(0)); post epoch
        __syncthreads();
        if (t < TT - 1 && tid == 0)
            __hip_atomic_store(&flags[m * 16 + jj], (unsigned int)(t + 1),
                               __ATOMIC_RELEASE, __HIP_MEMORY_SCOPE_AGENT);
    }
}

extern "C" void kernel_launch(void* const* d_in, const int* in_sizes, int n_in,
                              void* d_out, int out_size, void* d_ws, size_t ws_size,
                              hipStream_t stream) {
    const float* x   = (const float*)d_in[0];
    const float* wih = (const float*)d_in[1];
    const float* whh = (const float*)d_in[2];
    const float* bih = (const float*)d_in[3];
    const float* bhh = (const float*)d_in[4];
    float* out = (float*)d_out;

    unsigned int* hbu0  = (unsigned int*)d_ws;                      // 128 KB
    unsigned int* hbu1  = hbu0 + (size_t)BB * (HH / 2);             // 128 KB
    unsigned int* flags = (unsigned int*)((char*)d_ws + 262144);    // 64 u32

    // zero h buffer 0 (h0 = 0) and epoch flags (ws is poisoned 0xAA)
    hipMemsetAsync(d_ws, 0, 262144 + 256, stream);

    esn_kernel<<<dim3(64), dim3(256), 0, stream>>>(x, wih, whh, bih, bhh,
                                                   out, hbu0, hbu1, flags);
}

// Round 3
// 23682.207 us; speedup vs baseline: 2.6306x; 1.4325x over previous
//
#include <hip/hip_runtime.h>
#include <hip/hip_bf16.h>

// ESN recurrence on MI355X — R3: coalesced sc1 (LLC-coherent) h exchange.
// T=4096 steps, B=64, I=128, H=1024. out = h_T [64,1024] fp32.
//
// 64 blocks x 256 threads (4 waves). Wave (m, n_idx) owns output tile
// rows m*16..+15 (batch), cols n_idx*16..+15 (hidden). Whh/Wih N-slices
// in registers as hi/lo split bf16. h double-buffered in d_ws as
// block-major packed 2KB chunks [16 rows][32 u32], moved with inline-asm
// global_{load,store}_dwordx4 sc1 (agent-coherent at LLC, coalesced).
// Per-step sync: per-block epoch flags (release store after vmcnt(0)),
// relaxed polls by wave 0.

#define TT 4096
#define BB 64
#define II 128
#define HH 1024

typedef short bf16x8 __attribute__((ext_vector_type(8)));
typedef float f32x4 __attribute__((ext_vector_type(4)));
typedef unsigned int u32x4 __attribute__((ext_vector_type(4)));

__device__ __forceinline__ unsigned short f2bf(float f) {
    unsigned int u = __float_as_uint(f);
    u += 0x7FFFu + ((u >> 16) & 1u);   // RNE
    return (unsigned short)(u >> 16);
}
__device__ __forceinline__ float bf2f(unsigned short s) {
    return __uint_as_float(((unsigned int)s) << 16);
}

__device__ __forceinline__ u32x4 gload16_sc1(const unsigned int* p) {
    u32x4 r;
    asm volatile("global_load_dwordx4 %0, %1, off sc1"
                 : "=v"(r) : "v"(p) : "memory");
    return r;
}
__device__ __forceinline__ void gstore16_sc1(unsigned int* p, u32x4 v) {
    asm volatile("global_store_dwordx4 %0, %1, off sc1"
                 :: "v"(p), "v"(v) : "memory");
}

// 16B-chunk swizzle for h_lds (pitch 1032 shorts = 129 16B-chunks/row)
__device__ __forceinline__ int swz(int L) {
    return (L & 0x78) | (((L & 7) + (L >> 3)) & 7);
}

__global__ __launch_bounds__(256, 1) void esn_kernel(
    const float* __restrict__ x, const float* __restrict__ wih,
    const float* __restrict__ whh, const float* __restrict__ bih,
    const float* __restrict__ bhh, float* __restrict__ out,
    unsigned int* __restrict__ hbu0, unsigned int* __restrict__ hbu1,
    unsigned int* __restrict__ flags)
{
    __shared__ __align__(16) unsigned short h_lds[16 * 1032];  // 33 KB
    __shared__ __align__(16) unsigned short x_lds[16 * 136];   // 4.25 KB
    __shared__ __align__(16) unsigned int   c_lds[16 * 36];    // 2.25 KB

    const int tid  = threadIdx.x;
    const int lane = tid & 63;
    const int wv   = tid >> 6;
    const int col  = lane & 15;     // MFMA col (n) / A row (m)
    const int quad = lane >> 4;

    const int blk    = blockIdx.x;
    const int m      = blk >> 4;            // batch group 0..3
    const int m_base = m * 16;
    const int jj     = blk & 15;            // producer index within group
    const int n_idx  = jj * 4 + wv;
    const int n_base = n_idx * 16;

    // ---- one-time: weights into registers, hi/lo bf16 split ----
    bf16x8 bh[32], bl[32], ih_h[4], ih_l[4];
#pragma unroll
    for (int kt = 0; kt < 32; ++kt) {
        const float* p = whh + (size_t)(n_base + col) * HH + kt * 32 + quad * 8;
        bf16x8 hi, lo;
#pragma unroll
        for (int j = 0; j < 8; ++j) {
            float v = p[j];
            unsigned short h16 = f2bf(v);
            hi[j] = (short)h16;
            lo[j] = (short)f2bf(v - bf2f(h16));
        }
        bh[kt] = hi; bl[kt] = lo;
    }
#pragma unroll
    for (int kt = 0; kt < 4; ++kt) {
        const float* p = wih + (size_t)(n_base + col) * II + kt * 32 + quad * 8;
        bf16x8 hi, lo;
#pragma unroll
        for (int j = 0; j < 8; ++j) {
            float v = p[j];
            unsigned short h16 = f2bf(v);
            hi[j] = (short)h16;
            lo[j] = (short)f2bf(v - bf2f(h16));
        }
        ih_h[kt] = hi; ih_l[kt] = lo;
    }
    const float bias_sum = bih[n_base + col] + bhh[n_base + col];

    const int sr = tid >> 4;          // x-staging row 0..15
    const int sc = tid & 15;          // x-staging col group 0..15
    const int csrc = tid >> 4;        // h chunk index this thread loads 0..15
    const int crow = tid & 15;        // row within that chunk 0..15
    const unsigned int* fl = flags + m * 16;

    for (int t = 0; t < TT; ++t) {
        const unsigned int* rbu = (t & 1) ? hbu1 : hbu0;
        unsigned int*       wbu = (t & 1) ? hbu0 : hbu1;

        // stage x_t (16x128 fp32 -> bf16) -> LDS (overlaps poll latency)
        {
            const float* gp = x + (size_t)t * (BB * II) + (size_t)(m_base + sr) * II + sc * 8;
            bf16x8 v;
#pragma unroll
            for (int j = 0; j < 8; ++j) v[j] = (short)f2bf(gp[j]);
            *(bf16x8*)(x_lds + sr * 136 + sc * 8) = v;
        }

        // wait until every producer in this m-group has published h^t
        // (t=0: flags start at 0 >= 0, passes immediately; hbu0 is zeroed)
        if (wv == 0) {
            const bool skip = (lane >= 16);
            for (;;) {
                unsigned int v = 0;
                if (!skip)
                    v = __hip_atomic_load(fl + lane, __ATOMIC_RELAXED,
                                          __HIP_MEMORY_SCOPE_AGENT);
                if (__ballot(skip || v >= (unsigned int)t) == ~0ull) break;
            }
        }
        __syncthreads();

        // stage h^t: 16 chunks x 2KB, coalesced dwordx4 sc1 loads.
        // thread = (chunk csrc, row crow): one 32-u32 row = 8 dwordx4.
        {
            const unsigned int* gp = rbu + (size_t)(m * 16 + csrc) * 512 + crow * 32;
            u32x4 a0 = gload16_sc1(gp);
            u32x4 a1 = gload16_sc1(gp + 4);
            u32x4 a2 = gload16_sc1(gp + 8);
            u32x4 a3 = gload16_sc1(gp + 12);
            u32x4 a4 = gload16_sc1(gp + 16);
            u32x4 a5 = gload16_sc1(gp + 20);
            u32x4 a6 = gload16_sc1(gp + 24);
            u32x4 a7 = gload16_sc1(gp + 28);
            asm volatile("s_waitcnt vmcnt(0)"
                         : "+v"(a0), "+v"(a1), "+v"(a2), "+v"(a3),
                           "+v"(a4), "+v"(a5), "+v"(a6), "+v"(a7)
                         :: "memory");
            unsigned short* lp = h_lds + crow * 1032;
            // chunk csrc covers global cols csrc*64..+63 -> 16B-chunks L=csrc*8+k
            *(u32x4*)(lp + swz(csrc * 8 + 0) * 8) = a0;
            *(u32x4*)(lp + swz(csrc * 8 + 1) * 8) = a1;
            *(u32x4*)(lp + swz(csrc * 8 + 2) * 8) = a2;
            *(u32x4*)(lp + swz(csrc * 8 + 3) * 8) = a3;
            *(u32x4*)(lp + swz(csrc * 8 + 4) * 8) = a4;
            *(u32x4*)(lp + swz(csrc * 8 + 5) * 8) = a5;
            *(u32x4*)(lp + swz(csrc * 8 + 6) * 8) = a6;
            *(u32x4*)(lp + swz(csrc * 8 + 7) * 8) = a7;
        }
        __syncthreads();

        f32x4 acc = {0.f, 0.f, 0.f, 0.f};
        const unsigned short* arow = h_lds + col * 1032;
#pragma unroll
        for (int kt = 0; kt < 32; ++kt) {
            const int L = kt * 4 + quad;
            bf16x8 a = *(const bf16x8*)(arow + swz(L) * 8);
            acc = __builtin_amdgcn_mfma_f32_16x16x32_bf16(a, bh[kt], acc, 0, 0, 0);
            acc = __builtin_amdgcn_mfma_f32_16x16x32_bf16(a, bl[kt], acc, 0, 0, 0);
        }
        const unsigned short* xrow = x_lds + col * 136;
#pragma unroll
        for (int kt = 0; kt < 4; ++kt) {
            bf16x8 a = *(const bf16x8*)(xrow + kt * 32 + quad * 8);
            acc = __builtin_amdgcn_mfma_f32_16x16x32_bf16(a, ih_h[kt], acc, 0, 0, 0);
            acc = __builtin_amdgcn_mfma_f32_16x16x32_bf16(a, ih_l[kt], acc, 0, 0, 0);
        }

        // epilogue: bias + tanh; pack bf16 pairs into u32; even lanes hold
        // rows quad*4+0..3 at u32-col c = wv*8 + col/2 -> c_lds [16][36]
        float th[4];
#pragma unroll
        for (int i = 0; i < 4; ++i) {
            float pre = acc[i] + bias_sum;
            float pc  = fminf(fmaxf(pre, -9.f), 9.f);
            float e   = __expf(2.f * pc);
            th[i] = (e - 1.f) / (e + 1.f);
        }
        {
            unsigned int p01 = (unsigned int)f2bf(th[0]) |
                               ((unsigned int)f2bf(th[1]) << 16);
            unsigned int p23 = (unsigned int)f2bf(th[2]) |
                               ((unsigned int)f2bf(th[3]) << 16);
            unsigned int q01 = (unsigned int)__shfl_xor((int)p01, 1, 64);
            unsigned int q23 = (unsigned int)__shfl_xor((int)p23, 1, 64);
            if (!(lane & 1)) {
                unsigned int w0 = (p01 & 0xFFFFu) | (q01 << 16);
                unsigned int w1 = (p01 >> 16) | (q01 & 0xFFFF0000u);
                unsigned int w2 = (p23 & 0xFFFFu) | (q23 << 16);
                unsigned int w3 = (p23 >> 16) | (q23 & 0xFFFF0000u);
                const int c = wv * 8 + (col >> 1);
                unsigned int* cl = c_lds + (quad * 4) * 36 + c;
                cl[0]      = w0;
                cl[36]     = w1;
                cl[2 * 36] = w2;
                cl[3 * 36] = w3;
            }
        }
        if (t == TT - 1) {
#pragma unroll
            for (int i = 0; i < 4; ++i)
                out[(size_t)(m_base + quad * 4 + i) * HH + n_base + col] = th[i];
        }
        __syncthreads();

        // publish this block's 2KB chunk: 128 threads x one dwordx4 sc1
        if (tid < 128) {
            const int r  = tid >> 3;
            const int c0 = (tid & 7) * 4;
            u32x4 v = *(const u32x4*)(c_lds + r * 36 + c0);
            gstore16_sc1(wbu + (size_t)(m * 16 + jj) * 512 + r * 32 + c0, v);
        }
        asm volatile("s_waitcnt vmcnt(0)" ::: "memory");  // chunk at LLC
        __syncthreads();                                  // all waves done
        if (t < TT - 1 && tid == 0)
            __hip_atomic_store(&flags[m * 16 + jj], (unsigned int)(t + 1),
                               __ATOMIC_RELEASE, __HIP_MEMORY_SCOPE_AGENT);
    }
}

extern "C" void kernel_launch(void* const* d_in, const int* in_sizes, int n_in,
                              void* d_out, int out_size, void* d_ws, size_t ws_size,
                              hipStream_t stream) {
    const float* x   = (const float*)d_in[0];
    const float* wih = (const float*)d_in[1];
    const float* whh = (const float*)d_in[2];
    const float* bih = (const float*)d_in[3];
    const float* bhh = (const float*)d_in[4];
    float* out = (float*)d_out;

    unsigned int* hbu0  = (unsigned int*)d_ws;                      // 128 KB
    unsigned int* hbu1  = hbu0 + 32768;                             // 128 KB
    unsigned int* flags = (unsigned int*)((char*)d_ws + 262144);    // 64 u32

    // zero h buffer 0 (h0 = 0) and epoch flags (ws is poisoned 0xAA)
    hipMemsetAsync(d_ws, 0, 262144 + 256, stream);

    esn_kernel<<<dim3(64), dim3(256), 0, stream>>>(x, wih, whh, bih, bhh,
                                                   out, hbu0, hbu1, flags);
}

// Round 4
// 20545.139 us; speedup vs baseline: 3.0323x; 1.1527x over previous
//
#include <hip/hip_runtime.h>
#include <hip/hip_bf16.h>

// ESN recurrence on MI355X — R4: fence-free flag publish (no wbl2),
// raw sc1 poll, x software pipeline.
// T=4096 steps, B=64, I=128, H=1024. out = h_T [64,1024] fp32.
//
// 64 blocks x 256 threads (4 waves). Wave (m, n_idx) owns output tile
// rows m*16..+15 (batch), cols n_idx*16..+15 (hidden). Whh/Wih N-slices
// in registers as hi/lo split bf16. h double-buffered in d_ws as
// block-major packed 2KB chunks [16 rows][32 u32], moved with inline-asm
// global_{load,store}_dwordx4 sc1 (agent-coherent at LLC, coalesced).
// Per-step sync: per-block epoch flags. Publish = vmcnt(0) ack + barrier +
// plain sc1 dword store (data precedes flag at the coherence point).

#define TT 4096
#define BB 64
#define II 128
#define HH 1024

typedef short bf16x8 __attribute__((ext_vector_type(8)));
typedef float f32x4 __attribute__((ext_vector_type(4)));
typedef unsigned int u32x4 __attribute__((ext_vector_type(4)));

__device__ __forceinline__ unsigned short f2bf(float f) {
    unsigned int u = __float_as_uint(f);
    u += 0x7FFFu + ((u >> 16) & 1u);   // RNE
    return (unsigned short)(u >> 16);
}
__device__ __forceinline__ float bf2f(unsigned short s) {
    return __uint_as_float(((unsigned int)s) << 16);
}

__device__ __forceinline__ u32x4 gload16_sc1(const unsigned int* p) {
    u32x4 r;
    asm volatile("global_load_dwordx4 %0, %1, off sc1"
                 : "=v"(r) : "v"(p) : "memory");
    return r;
}
__device__ __forceinline__ void gstore16_sc1(unsigned int* p, u32x4 v) {
    asm volatile("global_store_dwordx4 %0, %1, off sc1"
                 :: "v"(p), "v"(v) : "memory");
}

// 16B-chunk swizzle for h_lds (pitch 1032 shorts = 129 16B-chunks/row)
__device__ __forceinline__ int swz(int L) {
    return (L & 0x78) | (((L & 7) + (L >> 3)) & 7);
}

__global__ __launch_bounds__(256, 1) void esn_kernel(
    const float* __restrict__ x, const float* __restrict__ wih,
    const float* __restrict__ whh, const float* __restrict__ bih,
    const float* __restrict__ bhh, float* __restrict__ out,
    unsigned int* __restrict__ hbu0, unsigned int* __restrict__ hbu1,
    unsigned int* __restrict__ flags)
{
    __shared__ __align__(16) unsigned short h_lds[16 * 1032];  // 33 KB
    __shared__ __align__(16) unsigned short x_lds[16 * 136];   // 4.25 KB
    __shared__ __align__(16) unsigned int   c_lds[16 * 36];    // 2.25 KB

    const int tid  = threadIdx.x;
    const int lane = tid & 63;
    const int wv   = tid >> 6;
    const int col  = lane & 15;     // MFMA col (n) / A row (m)
    const int quad = lane >> 4;

    const int blk    = blockIdx.x;
    const int m      = blk >> 4;            // batch group 0..3
    const int m_base = m * 16;
    const int jj     = blk & 15;            // producer index within group
    const int n_idx  = jj * 4 + wv;
    const int n_base = n_idx * 16;

    // ---- one-time: weights into registers, hi/lo bf16 split ----
    bf16x8 bh[32], bl[32], ih_h[4], ih_l[4];
#pragma unroll
    for (int kt = 0; kt < 32; ++kt) {
        const float* p = whh + (size_t)(n_base + col) * HH + kt * 32 + quad * 8;
        bf16x8 hi, lo;
#pragma unroll
        for (int j = 0; j < 8; ++j) {
            float v = p[j];
            unsigned short h16 = f2bf(v);
            hi[j] = (short)h16;
            lo[j] = (short)f2bf(v - bf2f(h16));
        }
        bh[kt] = hi; bl[kt] = lo;
    }
#pragma unroll
    for (int kt = 0; kt < 4; ++kt) {
        const float* p = wih + (size_t)(n_base + col) * II + kt * 32 + quad * 8;
        bf16x8 hi, lo;
#pragma unroll
        for (int j = 0; j < 8; ++j) {
            float v = p[j];
            unsigned short h16 = f2bf(v);
            hi[j] = (short)h16;
            lo[j] = (short)f2bf(v - bf2f(h16));
        }
        ih_h[kt] = hi; ih_l[kt] = lo;
    }
    const float bias_sum = bih[n_base + col] + bhh[n_base + col];

    const int sr = tid >> 4;          // x-staging row 0..15
    const int sc = tid & 15;          // x-staging col group 0..15
    const int csrc = tid >> 4;        // h chunk this thread loads 0..15
    const int crow = tid & 15;        // row within that chunk
    const unsigned int* fl = flags + m * 16;

    // x software pipeline: prefetch x_0 into registers
    f32x4 xa, xb;
    {
        const float* gp = x + (size_t)(m_base + sr) * II + sc * 8;
        xa = *(const f32x4*)gp;
        xb = *(const f32x4*)(gp + 4);
    }

    for (int t = 0; t < TT; ++t) {
        const unsigned int* rbu = (t & 1) ? hbu1 : hbu0;
        unsigned int*       wbu = (t & 1) ? hbu0 : hbu1;

        // convert prefetched x_t -> bf16 -> LDS
        {
            bf16x8 v;
#pragma unroll
            for (int j = 0; j < 4; ++j) v[j] = (short)f2bf(xa[j]);
#pragma unroll
            for (int j = 0; j < 4; ++j) v[4 + j] = (short)f2bf(xb[j]);
            *(bf16x8*)(x_lds + sr * 136 + sc * 8) = v;
        }

        // wait until every producer in this m-group has published h^t
        // (t=0: flags zeroed, v>=0 passes; hbu0 zeroed = h0)
        if (wv == 0) {
            const bool skip = (lane >= 16);
            const unsigned int* fp = fl + lane;
            for (;;) {
                unsigned int v = 0;
                if (!skip)
                    asm volatile("global_load_dword %0, %1, off sc1\n\t"
                                 "s_waitcnt vmcnt(0)"
                                 : "=v"(v) : "v"(fp) : "memory");
                if (__ballot(skip || v >= (unsigned int)t) == ~0ull) break;
            }
        }
        __syncthreads();

        // stage h^t: 16 chunks x 2KB, coalesced dwordx4 sc1 loads.
        {
            const unsigned int* gp = rbu + (size_t)(m * 16 + csrc) * 512 + crow * 32;
            u32x4 a0 = gload16_sc1(gp);
            u32x4 a1 = gload16_sc1(gp + 4);
            u32x4 a2 = gload16_sc1(gp + 8);
            u32x4 a3 = gload16_sc1(gp + 12);
            u32x4 a4 = gload16_sc1(gp + 16);
            u32x4 a5 = gload16_sc1(gp + 20);
            u32x4 a6 = gload16_sc1(gp + 24);
            u32x4 a7 = gload16_sc1(gp + 28);
            asm volatile("s_waitcnt vmcnt(0)"
                         : "+v"(a0), "+v"(a1), "+v"(a2), "+v"(a3),
                           "+v"(a4), "+v"(a5), "+v"(a6), "+v"(a7)
                         :: "memory");
            unsigned short* lp = h_lds + crow * 1032;
            *(u32x4*)(lp + swz(csrc * 8 + 0) * 8) = a0;
            *(u32x4*)(lp + swz(csrc * 8 + 1) * 8) = a1;
            *(u32x4*)(lp + swz(csrc * 8 + 2) * 8) = a2;
            *(u32x4*)(lp + swz(csrc * 8 + 3) * 8) = a3;
            *(u32x4*)(lp + swz(csrc * 8 + 4) * 8) = a4;
            *(u32x4*)(lp + swz(csrc * 8 + 5) * 8) = a5;
            *(u32x4*)(lp + swz(csrc * 8 + 6) * 8) = a6;
            *(u32x4*)(lp + swz(csrc * 8 + 7) * 8) = a7;
        }
        __syncthreads();

        // prefetch x_{t+1} (fills during MFMA + epilogue)
        if (t + 1 < TT) {
            const float* gp = x + (size_t)(t + 1) * (BB * II)
                              + (size_t)(m_base + sr) * II + sc * 8;
            xa = *(const f32x4*)gp;
            xb = *(const f32x4*)(gp + 4);
        }

        f32x4 acc = {0.f, 0.f, 0.f, 0.f};
        const unsigned short* arow = h_lds + col * 1032;
#pragma unroll
        for (int kt = 0; kt < 32; ++kt) {
            const int L = kt * 4 + quad;
            bf16x8 a = *(const bf16x8*)(arow + swz(L) * 8);
            acc = __builtin_amdgcn_mfma_f32_16x16x32_bf16(a, bh[kt], acc, 0, 0, 0);
            acc = __builtin_amdgcn_mfma_f32_16x16x32_bf16(a, bl[kt], acc, 0, 0, 0);
        }
        const unsigned short* xrow = x_lds + col * 136;
#pragma unroll
        for (int kt = 0; kt < 4; ++kt) {
            bf16x8 a = *(const bf16x8*)(xrow + kt * 32 + quad * 8);
            acc = __builtin_amdgcn_mfma_f32_16x16x32_bf16(a, ih_h[kt], acc, 0, 0, 0);
            acc = __builtin_amdgcn_mfma_f32_16x16x32_bf16(a, ih_l[kt], acc, 0, 0, 0);
        }

        // epilogue: bias + tanh; pack bf16 pairs into u32 -> c_lds [16][36]
        float th[4];
#pragma unroll
        for (int i = 0; i < 4; ++i) {
            float pre = acc[i] + bias_sum;
            float pc  = fminf(fmaxf(pre, -9.f), 9.f);
            float e   = __expf(2.f * pc);
            th[i] = (e - 1.f) / (e + 1.f);
        }
        {
            unsigned int p01 = (unsigned int)f2bf(th[0]) |
                               ((unsigned int)f2bf(th[1]) << 16);
            unsigned int p23 = (unsigned int)f2bf(th[2]) |
                               ((unsigned int)f2bf(th[3]) << 16);
            unsigned int q01 = (unsigned int)__shfl_xor((int)p01, 1, 64);
            unsigned int q23 = (unsigned int)__shfl_xor((int)p23, 1, 64);
            if (!(lane & 1)) {
                unsigned int w0 = (p01 & 0xFFFFu) | (q01 << 16);
                unsigned int w1 = (p01 >> 16) | (q01 & 0xFFFF0000u);
                unsigned int w2 = (p23 & 0xFFFFu) | (q23 << 16);
                unsigned int w3 = (p23 >> 16) | (q23 & 0xFFFF0000u);
                const int c = wv * 8 + (col >> 1);
                unsigned int* cl = c_lds + (quad * 4) * 36 + c;
                cl[0]      = w0;
                cl[36]     = w1;
                cl[2 * 36] = w2;
                cl[3 * 36] = w3;
            }
        }
        if (t == TT - 1) {
#pragma unroll
            for (int i = 0; i < 4; ++i)
                out[(size_t)(m_base + quad * 4 + i) * HH + n_base + col] = th[i];
        }
        __syncthreads();

        // publish this block's 2KB chunk: 128 threads x one dwordx4 sc1
        if (tid < 128) {
            const int r  = tid >> 3;
            const int c0 = (tid & 7) * 4;
            u32x4 v = *(const u32x4*)(c_lds + r * 36 + c0);
            gstore16_sc1(wbu + (size_t)(m * 16 + jj) * 512 + r * 32 + c0, v);
        }
        // ack at coherence point, then barrier, then plain sc1 flag store.
        // (data is at the LLC before the flag can be issued -> no wbl2 fence)
        asm volatile("s_waitcnt vmcnt(0)" ::: "memory");
        __syncthreads();
        if (t < TT - 1 && tid == 0) {
            unsigned int fv = (unsigned int)(t + 1);
            asm volatile("global_store_dword %0, %1, off sc1"
                         :: "v"(&flags[m * 16 + jj]), "v"(fv) : "memory");
        }
    }
}

extern "C" void kernel_launch(void* const* d_in, const int* in_sizes, int n_in,
                              void* d_out, int out_size, void* d_ws, size_t ws_size,
                              hipStream_t stream) {
    const float* x   = (const float*)d_in[0];
    const float* wih = (const float*)d_in[1];
    const float* whh = (const float*)d_in[2];
    const float* bih = (const float*)d_in[3];
    const float* bhh = (const float*)d_in[4];
    float* out = (float*)d_out;

    unsigned int* hbu0  = (unsigned int*)d_ws;                      // 128 KB
    unsigned int* hbu1  = hbu0 + 32768;                             // 128 KB
    unsigned int* flags = (unsigned int*)((char*)d_ws + 262144);    // 64 u32

    // zero h buffer 0 (h0 = 0) and epoch flags (ws is poisoned 0xAA)
    hipMemsetAsync(d_ws, 0, 262144 + 256, stream);

    esn_kernel<<<dim3(64), dim3(256), 0, stream>>>(x, wih, whh, bih, bhh,
                                                   out, hbu0, hbu1, flags);
}